// Round 4
// baseline (87.731 us; speedup 1.0000x reference)
//
#include <hip/hip_runtime.h>

#define NN 2048
#define KK 8
#define BB 32
#define TT 20

__global__ __launch_bounds__(1024) void osci_kernel(
    const float* __restrict__ coupling,   // [B,N,K]
    const float* __restrict__ phase0,     // [B,N]
    const float* __restrict__ omega,      // [B,N]
    const int*   __restrict__ conn,       // [N,K]
    float*       __restrict__ out)        // [T+1,B,N]
{
    const int b   = blockIdx.x;
    const int tid = threadIdx.x;
    const int wv  = tid >> 6;             // wave id 0..15
    const int i0  = tid * 2;              // thread owns oscillators i0, i0+1

    __shared__ float    ph_buf[2][NN];    // 16 KB double-buffered phase state
    __shared__ unsigned cnt[2][16][32];   // 4 KB per-(group,wave,bank) rank counters

    float ph[2], om[2];
    int   jj[2][KK];
    float vv[2][KK];

    // ---- coalesced setup loads + last-wins dedup (unchanged from R3) ----
    {
        const float2 p = ((const float2*)(phase0 + (size_t)b * NN))[tid];
        const float2 o = ((const float2*)(omega  + (size_t)b * NN))[tid];
        ph[0] = p.x; ph[1] = p.y;
        om[0] = o.x; om[1] = o.y;
        ((float2*)(out + (size_t)b * NN))[tid] = p;        // out[0,b,:]
        *(float2*)&ph_buf[0][i0] = p;

        #pragma unroll
        for (int t = 0; t < 2; ++t) {
            const int i = i0 + t;
            const int4   ja = ((const int4*)(conn + (size_t)i * KK))[0];
            const int4   jb = ((const int4*)(conn + (size_t)i * KK))[1];
            const float4 va = ((const float4*)(coupling + ((size_t)b * NN + i) * KK))[0];
            const float4 vb = ((const float4*)(coupling + ((size_t)b * NN + i) * KK))[1];
            int   jx[KK] = {ja.x, ja.y, ja.z, ja.w, jb.x, jb.y, jb.z, jb.w};
            float vx[KK] = {va.x, va.y, va.z, va.w, vb.x, vb.y, vb.z, vb.w};

            // last-wins scatter dedup: entry k vanishes if any k2>k hits same
            // column; n = count of surviving nonzero dense-row entries
            int cnt_nz = 0;
            #pragma unroll
            for (int k = 0; k < KK; ++k) {
                bool over = false;
                #pragma unroll
                for (int k2 = k + 1; k2 < KK; ++k2) over = over || (jx[k2] == jx[k]);
                if (over) vx[k] = 0.0f;
                if (vx[k] != 0.0f) ++cnt_nz;
            }
            const float nf = (float)cnt_nz;   // >= 1 (last write survives)
            #pragma unroll
            for (int k = 0; k < KK; ++k) { jj[t][k] = jx[k]; vv[t][k] = vx[k] / nf; }
        }
    }

    // zero rank counters (1024 entries, one per thread)
    ((unsigned*)cnt)[tid] = 0u;
    __syncthreads();

    // ---- one-time bank-balanced gather-slot assignment ----
    // Summation order within each accumulator is free, so permute each
    // oscillator's 8 neighbors across the 8 gather slots such that each
    // wave-level gather instruction has a near-flat bank histogram.
    // rank-within-bank mod 8 flattens each bank's per-slot load to ~2
    // (the free 2-way threshold); rotate+ffs resolves per-lane collisions.
    int   jS[2][KK];
    float wS[2][KK];
    #pragma unroll
    for (int g = 0; g < 2; ++g) {
        unsigned slotpack = 0u;           // 8 x 4-bit slot ids
        unsigned free_m   = 0xFFu;
        #pragma unroll
        for (int m = 0; m < KK; ++m) {
            const unsigned bank = (unsigned)jj[g][m] & 31u;
            const unsigned r    = atomicAdd(&cnt[g][wv][bank], 1u);
            const unsigned p    = r & 7u;
            const unsigned rot  = ((free_m >> p) | (free_m << (8u - p))) & 0xFFu;
            const unsigned d    = (unsigned)__ffs((int)rot) - 1u;
            const unsigned s    = (p + d) & 7u;
            free_m &= ~(1u << s);
            slotpack |= s << (m * 4);
        }
        #pragma unroll
        for (int s = 0; s < KK; ++s) {
            int jv = 0; float wvv = 0.0f;
            #pragma unroll
            for (int m = 0; m < KK; ++m) {
                const bool hit = (((slotpack >> (m * 4)) & 7u) == (unsigned)s);
                jv  = hit ? jj[g][m] : jv;
                wvv = hit ? vv[g][m] : wvv;
            }
            jS[g][s] = jv; wS[g][s] = wvv;
        }
    }
    __syncthreads();

    // ---- time-step loop ----
    for (int step = 0; step < TT; ++step) {
        const int cur = step & 1;
        const int nxt = cur ^ 1;

        const float ri0 = ph[0], ri1 = ph[1];
        float acc0 = 0.0f, acc1 = 0.0f;
        // Cs*c - Cc*s == sum_k w_k * sin(phi_jk - phi_i)
        #pragma unroll
        for (int k = 0; k < KK; ++k) {
            const float pj0 = ph_buf[cur][jS[0][k]];
            const float pj1 = ph_buf[cur][jS[1][k]];
            acc0 += wS[0][k] * __sinf(pj0 - ri0);
            acc1 += wS[1][k] * __sinf(pj1 - ri1);
        }
        const float pn0 = ri0 + acc0 + om[0];   // eps=1, ANNEAL=0
        const float pn1 = ri1 + acc1 + om[1];
        ph[0] = pn0; ph[1] = pn1;

        *(float2*)&ph_buf[nxt][i0] = make_float2(pn0, pn1);           // ds_write_b64
        *(float2*)&out[((size_t)(step + 1) * BB + b) * NN + i0] = make_float2(pn0, pn1);

        __syncthreads();   // writes to nxt visible before next step's gathers
    }
}

extern "C" void kernel_launch(void* const* d_in, const int* in_sizes, int n_in,
                              void* d_out, int out_size, void* d_ws, size_t ws_size,
                              hipStream_t stream) {
    const float* coupling = (const float*)d_in[0];   // [B,N,K]
    const float* phase0   = (const float*)d_in[1];   // [B,N]
    const float* omega    = (const float*)d_in[2];   // [B,N]
    const int*   conn     = (const int*)d_in[3];     // [N,K]
    float* out = (float*)d_out;                      // [T+1,B,N]

    osci_kernel<<<BB, 1024, 0, stream>>>(coupling, phase0, omega, conn, out);
}

// Round 5
// 84.324 us; speedup vs baseline: 1.0404x; 1.0404x over previous
//
#include <hip/hip_runtime.h>

#define NN 2048
#define KK 8
#define BB 32
#define TT 20

__global__ __launch_bounds__(1024) void osci_kernel(
    const float* __restrict__ coupling,   // [B,N,K]
    const float* __restrict__ phase0,     // [B,N]
    const float* __restrict__ omega,      // [B,N]
    const int*   __restrict__ conn,       // [N,K]
    float*       __restrict__ out)        // [T+1,B,N]
{
    const int b   = blockIdx.x;
    const int tid = threadIdx.x;
    const int i0  = tid * 2;              // thread owns oscillators i0, i0+1

    // double-buffered phase state: one barrier per step
    __shared__ float ph_buf[2][NN];

    int   cidx[2][KK];
    float w[2][KK];
    float om[2];
    float ph[2];

    // ---- coalesced setup loads (pair mapping => wide vectors) ----
    {
        const float2 p = ((const float2*)(phase0 + (size_t)b * NN))[tid];
        const float2 o = ((const float2*)(omega  + (size_t)b * NN))[tid];
        ph[0] = p.x; ph[1] = p.y;
        om[0] = o.x; om[1] = o.y;
        ((float2*)(out + (size_t)b * NN))[tid] = p;        // out[0,b,:]
        *(float2*)&ph_buf[0][i0] = p;

        #pragma unroll
        for (int t = 0; t < 2; ++t) {
            const int i = i0 + t;
            const int4   ja = ((const int4*)(conn + (size_t)i * KK))[0];
            const int4   jb = ((const int4*)(conn + (size_t)i * KK))[1];
            const float4 va = ((const float4*)(coupling + ((size_t)b * NN + i) * KK))[0];
            const float4 vb = ((const float4*)(coupling + ((size_t)b * NN + i) * KK))[1];
            int   jj[KK] = {ja.x, ja.y, ja.z, ja.w, jb.x, jb.y, jb.z, jb.w};
            float vv[KK] = {va.x, va.y, va.z, va.w, vb.x, vb.y, vb.z, vb.w};

            // last-wins scatter dedup: entry k vanishes if any k2>k hits same
            // column; n = count of surviving nonzero dense-row entries
            int cnt = 0;
            #pragma unroll
            for (int k = 0; k < KK; ++k) {
                bool over = false;
                #pragma unroll
                for (int k2 = k + 1; k2 < KK; ++k2) over = over || (jj[k2] == jj[k]);
                if (over) vv[k] = 0.0f;
                if (vv[k] != 0.0f) ++cnt;
            }
            const float nf = (float)cnt;      // cnt >= 1 (last write survives)
            #pragma unroll
            for (int k = 0; k < KK; ++k) {
                cidx[t][k] = jj[k];
                w[t][k]    = vv[k] / nf;      // fold 1/n into weights (setup-only)
            }
        }
    }
    __syncthreads();

    // output pointer for out[step+1, b, i0], advanced by B*N floats per step
    float2* outp = (float2*)(out + ((size_t)BB + b) * NN + i0);

    for (int step = 0; step < TT; ++step) {
        const int cur = step & 1;
        const int nxt = cur ^ 1;

        const float ri0 = ph[0], ri1 = ph[1];
        float acc0 = 0.0f, acc1 = 0.0f;
        // Cs*c - Cc*s == sum_k w_k * sin(phi_jk - phi_i); both oscillators
        // interleaved for ILP on the LDS gathers + v_sin chain
        #pragma unroll
        for (int k = 0; k < KK; ++k) {
            const float pj0 = ph_buf[cur][cidx[0][k]];
            const float pj1 = ph_buf[cur][cidx[1][k]];
            acc0 += w[0][k] * __sinf(pj0 - ri0);
            acc1 += w[1][k] * __sinf(pj1 - ri1);
        }
        const float pn0 = ri0 + acc0 + om[0];   // eps=1, ANNEAL=0
        const float pn1 = ri1 + acc1 + om[1];
        ph[0] = pn0; ph[1] = pn1;

        *(float2*)&ph_buf[nxt][i0] = make_float2(pn0, pn1);   // ds_write_b64
        *outp = make_float2(pn0, pn1);
        outp += (size_t)(BB * NN) / 2;

        if (step < TT - 1) __syncthreads();   // last step: no one reads ph_buf again
    }
}

extern "C" void kernel_launch(void* const* d_in, const int* in_sizes, int n_in,
                              void* d_out, int out_size, void* d_ws, size_t ws_size,
                              hipStream_t stream) {
    const float* coupling = (const float*)d_in[0];   // [B,N,K]
    const float* phase0   = (const float*)d_in[1];   // [B,N]
    const float* omega    = (const float*)d_in[2];   // [B,N]
    const int*   conn     = (const int*)d_in[3];     // [N,K]
    float* out = (float*)d_out;                      // [T+1,B,N]

    osci_kernel<<<BB, 1024, 0, stream>>>(coupling, phase0, omega, conn, out);
}